// Round 7
// baseline (133.386 us; speedup 1.0000x reference)
//
#include <hip/hip_runtime.h>
#include <math.h>

// Problem constants (from reference): B,C,N,D,S = 512,256,2048,64,3
constexpr int Bb = 512;
constexpr int Cc = 256;
constexpr int Nn = 2048;
constexpr int Dd = 64;
constexpr int EMIT = Dd + 1 + 1 + 3 + 1;  // 70
constexpr int NW = 16;                    // waves in a 1024-thread block

// Workspace layout (floats):
//   [0, 512*80)                : per-row k[64] + scalars{beta,g,s0,s1,s2,gamma,kinv} (stride 80)
//   [Z_OFF, Z_OFF+512*2048)    : z[b][n] = beta*cos
//   [ZMAX_OFF, +512)           : per-row max of z
constexpr int FC_STRIDE = 80;
constexpr int Z_OFF     = Bb * FC_STRIDE;              // 40960
constexpr int ZMAX_OFF  = Z_OFF + Bb * Nn;             // 40960 + 1048576

// ---------------- k0: fc = tanh(co @ W + b) + head scalars -> ws ----------
__global__ __launch_bounds__(256)
void k0_fc(const float* __restrict__ co, const float* __restrict__ W,
           const float* __restrict__ bias, float* __restrict__ ws)
{
    const int b = blockIdx.x, t = threadIdx.x;
    __shared__ float part[3][EMIT];
    __shared__ float fcrow[EMIT];
    const float* corow = co + (size_t)b * Cc;

    if (t < 210) {
        const int j = t % EMIT, p = t / EMIT;      // p = 0..2
        const int c0 = p * 86, c1 = (p == 2) ? Cc : c0 + 86;
        float s = 0.f;
        for (int c = c0; c < c1; ++c)
            s = fmaf(corow[c], W[(size_t)c * EMIT + j], s);
        part[p][j] = s;
    }
    __syncthreads();
    if (t < EMIT)
        fcrow[t] = tanhf(bias[t] + part[0][t] + part[1][t] + part[2][t]);
    __syncthreads();

    float* wsrow = ws + (size_t)b * FC_STRIDE;
    if (t < 64) {                                   // wave 0
        float kk = fcrow[t];
        wsrow[t] = kk;
        float ksq = kk * kk;
        #pragma unroll
        for (int o = 1; o < 64; o <<= 1) ksq += __shfl_xor(ksq, o);
        if (t == 0) {
            float kinv  = 1.f / sqrtf(ksq);
            float beta  = log1pf(expf(fcrow[Dd]));
            float g     = 1.f / (1.f + expf(-fcrow[Dd + 1]));
            float f0 = fcrow[Dd + 2], f1 = fcrow[Dd + 3], f2 = fcrow[Dd + 4];
            float mx = fmaxf(f0, fmaxf(f1, f2));
            float e0 = expf(f0 - mx), e1 = expf(f1 - mx), e2 = expf(f2 - mx);
            float ei = 1.f / (e0 + e1 + e2);
            float gamma = 1.f + log1pf(expf(fcrow[Dd + 5]));
            wsrow[64] = beta; wsrow[65] = g;
            wsrow[66] = e0 * ei; wsrow[67] = e1 * ei; wsrow[68] = e2 * ei;
            wsrow[69] = gamma; wsrow[70] = kinv;
        }
    }
}

// ---------------- k1a: pure M stream -> z[b][n], zmax[b] -------------------
__global__ __launch_bounds__(1024, 8)
void k1a_cos(const float* __restrict__ M, float* __restrict__ ws)
{
    const int b = blockIdx.x, t = threadIdx.x;
    const int lane = t & 63, wv = t >> 6;
    __shared__ __align__(16) float kf[72];
    __shared__ float redA[NW];

    if (t < 72) kf[t] = ws[(size_t)b * FC_STRIDE + t];
    __syncthreads();

    const float bk = kf[64] * kf[70];               // beta * (1/|k|)
    const int rg = t >> 2, p = t & 3;
    const float4 k0 = *(const float4*)&kf[p * 16 + 0];
    const float4 k1 = *(const float4*)&kf[p * 16 + 4];
    const float4 k2 = *(const float4*)&kf[p * 16 + 8];
    const float4 k3 = *(const float4*)&kf[p * 16 + 12];

    const size_t mbase = (size_t)b * Nn * Dd;
    float* zrow = ws + Z_OFF + (size_t)b * Nn;
    float lmax = -3.4e38f;

    #pragma unroll 2
    for (int n0 = 0; n0 < Nn; n0 += 256) {
        const int n = n0 + rg;
        const float4* mr = (const float4*)&M[mbase + (size_t)n * Dd + p * 16];
        const float4 m0 = mr[0], m1 = mr[1], m2 = mr[2], m3 = mr[3];
        float dot = m0.x*k0.x + m0.y*k0.y + m0.z*k0.z + m0.w*k0.w
                  + m1.x*k1.x + m1.y*k1.y + m1.z*k1.z + m1.w*k1.w
                  + m2.x*k2.x + m2.y*k2.y + m2.z*k2.z + m2.w*k2.w
                  + m3.x*k3.x + m3.y*k3.y + m3.z*k3.z + m3.w*k3.w;
        float msq = m0.x*m0.x + m0.y*m0.y + m0.z*m0.z + m0.w*m0.w
                  + m1.x*m1.x + m1.y*m1.y + m1.z*m1.z + m1.w*m1.w
                  + m2.x*m2.x + m2.y*m2.y + m2.z*m2.z + m2.w*m2.w
                  + m3.x*m3.x + m3.y*m3.y + m3.z*m3.z + m3.w*m3.w;
        dot += __shfl_xor(dot, 1);
        msq += __shfl_xor(msq, 1);
        dot += __shfl_xor(dot, 2);
        msq += __shfl_xor(msq, 2);
        if (p == 0) {
            float z = bk * dot / sqrtf(msq);
            zrow[n] = z;
            lmax = fmaxf(lmax, z);
        }
    }
    #pragma unroll
    for (int o = 1; o < 64; o <<= 1) lmax = fmaxf(lmax, __shfl_xor(lmax, o));
    if (lane == 0) redA[wv] = lmax;
    __syncthreads();
    if (t == 0) {
        float zmax = redA[0];
        #pragma unroll
        for (int w = 1; w < NW; ++w) zmax = fmaxf(zmax, redA[w]);
        ws[ZMAX_OFF + b] = zmax;
    }
}

// ---------------- k1b: softmax + gate + conv + pow + norm -> w_t -----------
__global__ __launch_bounds__(1024, 8)
void k1b_weights(const float* __restrict__ wprev, float* __restrict__ ws,
                 float* __restrict__ out_w)
{
    const int b = blockIdx.x, t = threadIdx.x;
    const int lane = t & 63, wv = t >> 6;
    __shared__ float zbuf[Nn];
    __shared__ float wpbuf[Nn];
    __shared__ float kf[72];
    __shared__ float redA[NW], redB[NW];

    if (t < 72) kf[t] = ws[(size_t)b * FC_STRIDE + t];
    {
        const float* wpv = wprev + (size_t)b * Nn;
        wpbuf[t]        = wpv[t];
        wpbuf[t + 1024] = wpv[t + 1024];
    }
    const float zmax = ws[ZMAX_OFF + b];
    const float* zrow = ws + Z_OFF + (size_t)b * Nn;

    // exp + sum
    float ls = 0.f;
    float e0_ = __expf(zrow[t] - zmax);
    float e1_ = __expf(zrow[t + 1024] - zmax);
    ls = e0_ + e1_;
    __syncthreads();               // kf/wpbuf visible; zbuf safe to write
    zbuf[t] = e0_;
    zbuf[t + 1024] = e1_;
    #pragma unroll
    for (int o = 1; o < 64; o <<= 1) ls += __shfl_xor(ls, o);
    if (lane == 0) redB[wv] = ls;
    __syncthreads();               // zbuf + redB ready
    float Zs = 0.f;
    #pragma unroll
    for (int w = 0; w < NW; ++w) Zs += redB[w];

    // conv + pow + sum (gate folded algebraically)
    const float g  = kf[65];
    const float A  = g / Zs;
    const float Cg = 1.f - g;
    const float s0 = kf[66], s1 = kf[67], s2 = kf[68], gamma = kf[69];
    float wr0, wr1, lsum;
    {
        const int n  = t;
        const int np = (n + 1) & (Nn - 1), nm = (n - 1) & (Nn - 1);
        wr0 = __powf(A * (s0 * zbuf[np] + s1 * zbuf[n] + s2 * zbuf[nm])
                   + Cg * (s0 * wpbuf[np] + s1 * wpbuf[n] + s2 * wpbuf[nm]), gamma);
    }
    {
        const int n  = t + 1024;
        const int np = (n + 1) & (Nn - 1), nm = (n - 1) & (Nn - 1);
        wr1 = __powf(A * (s0 * zbuf[np] + s1 * zbuf[n] + s2 * zbuf[nm])
                   + Cg * (s0 * wpbuf[np] + s1 * wpbuf[n] + s2 * wpbuf[nm]), gamma);
    }
    lsum = wr0 + wr1;
    #pragma unroll
    for (int o = 1; o < 64; o <<= 1) lsum += __shfl_xor(lsum, o);
    if (lane == 0) redA[wv] = lsum;
    __syncthreads();
    float Ws = 0.f;
    #pragma unroll
    for (int w = 0; w < NW; ++w) Ws += redA[w];

    const float inv = 1.f / Ws;
    float* ow = out_w + (size_t)b * Nn;
    ow[t]        = wr0 * inv;
    ow[t + 1024] = wr1 * inv;
}

// ---------------- k2: r_t[d] = sum_n w_t[n] * M[b,n,d]  (descending n) -----
__global__ __launch_bounds__(1024, 8)
void k2_read(const float* __restrict__ M, const float* __restrict__ out_w,
             float* __restrict__ out_r)
{
    const int b = blockIdx.x, t = threadIdx.x;
    const int lane = t & 63, wv = t >> 6;
    __shared__ float wtbuf[Nn];
    __shared__ float rred[NW][Dd];

    const float* wrow = out_w + (size_t)b * Nn;
    wtbuf[t]        = wrow[t];
    wtbuf[t + 1024] = wrow[t + 1024];
    __syncthreads();

    const size_t mbase = (size_t)b * Nn * Dd;
    const int grp = t >> 4;          // 64 rows per iteration
    const int dk  = t & 15;
    float4 acc = make_float4(0.f, 0.f, 0.f, 0.f);
    #pragma unroll 4
    for (int i = 0; i < Nn / 64; ++i) {
        const int n = (Nn - 64) - i * 64 + grp;   // descending blocks of 64
        const float w = wtbuf[n];
        const float4 m = *(const float4*)&M[mbase + (size_t)n * Dd + dk * 4];
        acc.x += w * m.x; acc.y += w * m.y;
        acc.z += w * m.z; acc.w += w * m.w;
    }
    #pragma unroll
    for (int o = 16; o < 64; o <<= 1) {
        acc.x += __shfl_xor(acc.x, o);
        acc.y += __shfl_xor(acc.y, o);
        acc.z += __shfl_xor(acc.z, o);
        acc.w += __shfl_xor(acc.w, o);
    }
    if (lane < 16) {
        rred[wv][lane * 4 + 0] = acc.x;
        rred[wv][lane * 4 + 1] = acc.y;
        rred[wv][lane * 4 + 2] = acc.z;
        rred[wv][lane * 4 + 3] = acc.w;
    }
    __syncthreads();
    if (t < Dd) {
        float r = 0.f;
        #pragma unroll
        for (int w = 0; w < NW; ++w) r += rred[w][t];
        out_r[(size_t)b * Dd + t] = r;
    }
}

extern "C" void kernel_launch(void* const* d_in, const int* in_sizes, int n_in,
                              void* d_out, int out_size, void* d_ws, size_t ws_size,
                              hipStream_t stream) {
    const float* co    = (const float*)d_in[0];   // (B, C)
    const float* wprev = (const float*)d_in[1];   // (B, N)
    const float* M     = (const float*)d_in[2];   // (B, N, D)
    const float* W     = (const float*)d_in[3];   // (C, 70)
    const float* bias  = (const float*)d_in[4];   // (70,)
    float* out   = (float*)d_out;                 // r_t (B*D) then w_t (B*N)
    float* out_r = out;
    float* out_w = out + (size_t)Bb * Dd;
    float* ws    = (float*)d_ws;                  // needs ~4.4 MB

    k0_fc      <<<Bb, 256,  0, stream>>>(co, W, bias, ws);
    k1a_cos    <<<Bb, 1024, 0, stream>>>(M, ws);
    k1b_weights<<<Bb, 1024, 0, stream>>>(wprev, ws, out_w);
    k2_read    <<<Bb, 1024, 0, stream>>>(M, out_w, out_r);
}

// Round 8
// 131.849 us; speedup vs baseline: 1.0117x; 1.0117x over previous
//
#include <hip/hip_runtime.h>
#include <math.h>

// Problem constants (from reference): B,C,N,D,S = 512,256,2048,64,3
constexpr int Bb = 512;
constexpr int Cc = 256;
constexpr int Nn = 2048;
constexpr int Dd = 64;
constexpr int EMIT = Dd + 1 + 1 + 3 + 1;  // 70
constexpr int BLOCK = 1024;
constexpr int NW = BLOCK / 64;            // 16 waves
constexpr int GRID = Bb / 2;              // 2 rows per block

// fcX[0..63] = k, fcX[64]=beta, [65]=g, [66..68]=s, [69]=gamma, [70]=1/|k|
__global__ __launch_bounds__(BLOCK, 4)
void ntm_read_head_kernel(const float* __restrict__ co,
                          const float* __restrict__ wprev,
                          const float* __restrict__ M,
                          const float* __restrict__ W,
                          const float* __restrict__ bias,
                          float* __restrict__ out_r,
                          float* __restrict__ out_w)
{
    const int r0 = blockIdx.x * 2;
    const int r1 = r0 + 1;
    const int t    = threadIdx.x;
    const int lane = t & 63;
    const int wv   = t >> 6;

    __shared__ __align__(16) float fc0[72], fc1[72];
    __shared__ __align__(16) float zbuf0[Nn], zbuf1[Nn];   // also fc scratch
    __shared__ float wp0[Nn], wp1[Nn];
    __shared__ float wt0[Nn], wt1[Nn];
    __shared__ float redA[NW], redB[NW];
    __shared__ float rred[NW][Dd];

    // ---------- preload w_prev rows ----------
    {
        const float* a = wprev + (size_t)r0 * Nn;
        const float* b = wprev + (size_t)r1 * Nn;
        wp0[t] = a[t];  wp0[t + 1024] = a[t + 1024];
        wp1[t] = b[t];  wp1[t + 1024] = b[t + 1024];
    }

    // ---------- fc for both rows (scratch in zbuf0/zbuf1) ----------
    {
        const float* co0 = co + (size_t)r0 * Cc;
        const float* co1 = co + (size_t)r1 * Cc;
        if (t < 980) {
            const int j = t % EMIT, part = t / EMIT;      // part 0..13
            const int c0 = part * 19;
            const int c1 = (c0 + 19 < Cc) ? c0 + 19 : Cc;
            float sA = 0.f, sB = 0.f;
            for (int c = c0; c < c1; ++c) {
                const float w = W[(size_t)c * EMIT + j];
                sA = fmaf(co0[c], w, sA);
                sB = fmaf(co1[c], w, sB);
            }
            zbuf0[part * EMIT + j] = sA;
            zbuf1[part * EMIT + j] = sB;
        }
        __syncthreads();
        if (t < EMIT) {
            float s = bias[t];
            #pragma unroll
            for (int w = 0; w < 14; ++w) s += zbuf0[w * EMIT + t];
            fc0[t] = tanhf(s);
        } else if (t >= 512 && t < 512 + EMIT) {
            const int j = t - 512;
            float s = bias[j];
            #pragma unroll
            for (int w = 0; w < 14; ++w) s += zbuf1[w * EMIT + j];
            fc1[j] = tanhf(s);
        }
        __syncthreads();
    }

    // ---------- head scalars: wave0 -> r0, wave1 -> r1 ----------
    if (t < 128) {
        float* fcX = (t < 64) ? fc0 : fc1;
        const int l = t & 63;
        float kk  = fcX[l];
        float ksq = kk * kk;
        #pragma unroll
        for (int o = 1; o < 64; o <<= 1) ksq += __shfl_xor(ksq, o);
        if (l == 0) {
            float kinv  = 1.f / sqrtf(ksq);
            float beta  = log1pf(expf(fcX[Dd]));
            float g     = 1.f / (1.f + expf(-fcX[Dd + 1]));
            float f0 = fcX[Dd + 2], f1 = fcX[Dd + 3], f2 = fcX[Dd + 4];
            float mx = fmaxf(f0, fmaxf(f1, f2));
            float e0 = expf(f0 - mx), e1 = expf(f1 - mx), e2 = expf(f2 - mx);
            float ei = 1.f / (e0 + e1 + e2);
            float gamma = 1.f + log1pf(expf(fcX[Dd + 5]));
            fcX[64] = beta; fcX[65] = g;
            fcX[66] = e0 * ei; fcX[67] = e1 * ei; fcX[68] = e2 * ei;
            fcX[69] = gamma; fcX[70] = kinv;
        }
    }
    __syncthreads();

    const size_t mb0 = (size_t)r0 * Nn * Dd;
    const size_t mb1 = (size_t)r1 * Nn * Dd;
    const int rg = t >> 2, p = t & 3;        // pass1 mapping: 4 lanes/row
    const int grp = t >> 4, dk = t & 15;     // pass2 mapping: 16 lanes/row

    // ---------- pass1(r0): HBM stream, fused running max ----------
    float lmax0 = -3.4e38f;
    {
        const float bk = fc0[64] * fc0[70];
        const float4 k0 = *(const float4*)&fc0[p * 16 + 0];
        const float4 k1 = *(const float4*)&fc0[p * 16 + 4];
        const float4 k2 = *(const float4*)&fc0[p * 16 + 8];
        const float4 k3 = *(const float4*)&fc0[p * 16 + 12];
        #pragma unroll 2
        for (int n0 = 0; n0 < Nn; n0 += 256) {
            const int n = n0 + rg;
            const float4* mr = (const float4*)&M[mb0 + (size_t)n * Dd + p * 16];
            const float4 m0 = mr[0], m1 = mr[1], m2 = mr[2], m3 = mr[3];
            float dot = m0.x*k0.x + m0.y*k0.y + m0.z*k0.z + m0.w*k0.w
                      + m1.x*k1.x + m1.y*k1.y + m1.z*k1.z + m1.w*k1.w
                      + m2.x*k2.x + m2.y*k2.y + m2.z*k2.z + m2.w*k2.w
                      + m3.x*k3.x + m3.y*k3.y + m3.z*k3.z + m3.w*k3.w;
            float msq = m0.x*m0.x + m0.y*m0.y + m0.z*m0.z + m0.w*m0.w
                      + m1.x*m1.x + m1.y*m1.y + m1.z*m1.z + m1.w*m1.w
                      + m2.x*m2.x + m2.y*m2.y + m2.z*m2.z + m2.w*m2.w
                      + m3.x*m3.x + m3.y*m3.y + m3.z*m3.z + m3.w*m3.w;
            dot += __shfl_xor(dot, 1);  msq += __shfl_xor(msq, 1);
            dot += __shfl_xor(dot, 2);  msq += __shfl_xor(msq, 2);
            if (p == 0) {
                float z = bk * dot / sqrtf(msq);
                zbuf0[n] = z;
                lmax0 = fmaxf(lmax0, z);
            }
        }
    }
    #pragma unroll
    for (int o = 1; o < 64; o <<= 1) lmax0 = fmaxf(lmax0, __shfl_xor(lmax0, o));
    if (lane == 0) redA[wv] = lmax0;
    __syncthreads();                                   // zbuf0 + redA
    float zmax0 = redA[0];
    #pragma unroll
    for (int w = 1; w < NW; ++w) zmax0 = fmaxf(zmax0, redA[w]);

    // ---------- mid(r0): exp+sum, conv+pow+sum, normalize ----------
    {
        float e0 = __expf(zbuf0[t] - zmax0);
        float e1 = __expf(zbuf0[t + 1024] - zmax0);
        float ls = e0 + e1;
        zbuf0[t] = e0; zbuf0[t + 1024] = e1;
        #pragma unroll
        for (int o = 1; o < 64; o <<= 1) ls += __shfl_xor(ls, o);
        if (lane == 0) redB[wv] = ls;
    }
    __syncthreads();                                   // exp'd zbuf0 + redB
    {
        float Zs = 0.f;
        #pragma unroll
        for (int w = 0; w < NW; ++w) Zs += redB[w];
        const float g  = fc0[65];
        const float A  = g / Zs, Cg = 1.f - g;
        const float s0 = fc0[66], s1 = fc0[67], s2 = fc0[68], gamma = fc0[69];
        float wr0, wr1;
        {
            const int n = t, np = (n + 1) & (Nn - 1), nm = (n - 1) & (Nn - 1);
            wr0 = __powf(A * (s0 * zbuf0[np] + s1 * zbuf0[n] + s2 * zbuf0[nm])
                       + Cg * (s0 * wp0[np] + s1 * wp0[n] + s2 * wp0[nm]), gamma);
        }
        {
            const int n = t + 1024, np = (n + 1) & (Nn - 1), nm = (n - 1) & (Nn - 1);
            wr1 = __powf(A * (s0 * zbuf0[np] + s1 * zbuf0[n] + s2 * zbuf0[nm])
                       + Cg * (s0 * wp0[np] + s1 * wp0[n] + s2 * wp0[nm]), gamma);
        }
        float lsum = wr0 + wr1;
        #pragma unroll
        for (int o = 1; o < 64; o <<= 1) lsum += __shfl_xor(lsum, o);
        if (lane == 0) redA[wv] = lsum;
        __syncthreads();
        float Ws = 0.f;
        #pragma unroll
        for (int w = 0; w < NW; ++w) Ws += redA[w];
        const float inv = 1.f / Ws;
        float* ow = out_w + (size_t)r0 * Nn;
        wt0[t] = wr0 * inv;        ow[t] = wr0 * inv;
        wt0[t + 1024] = wr1 * inv; ow[t + 1024] = wr1 * inv;
    }
    __syncthreads();                                   // wt0 final

    // ---------- pipelined: pass1(r1) [HBM] ∥ pass2(r0) [L3] ----------
    float lmax1 = -3.4e38f;
    float4 acc0 = make_float4(0.f, 0.f, 0.f, 0.f);
    {
        const float bk = fc1[64] * fc1[70];
        const float4 k0 = *(const float4*)&fc1[p * 16 + 0];
        const float4 k1 = *(const float4*)&fc1[p * 16 + 4];
        const float4 k2 = *(const float4*)&fc1[p * 16 + 8];
        const float4 k3 = *(const float4*)&fc1[p * 16 + 12];
        for (int i = 0; i < 8; ++i) {
            const int n = i * 256 + rg;
            const float4* mr = (const float4*)&M[mb1 + (size_t)n * Dd + p * 16];
            const float4 m0 = mr[0], m1 = mr[1], m2 = mr[2], m3 = mr[3];
            // pass2(r0): 4 sub-chunks of 64 rows (L3-resident)
            #pragma unroll
            for (int jj = 0; jj < 4; ++jj) {
                const int n2 = i * 256 + jj * 64 + grp;
                const float w = wt0[n2];
                const float4 mm = *(const float4*)&M[mb0 + (size_t)n2 * Dd + dk * 4];
                acc0.x += w * mm.x; acc0.y += w * mm.y;
                acc0.z += w * mm.z; acc0.w += w * mm.w;
            }
            float dot = m0.x*k0.x + m0.y*k0.y + m0.z*k0.z + m0.w*k0.w
                      + m1.x*k1.x + m1.y*k1.y + m1.z*k1.z + m1.w*k1.w
                      + m2.x*k2.x + m2.y*k2.y + m2.z*k2.z + m2.w*k2.w
                      + m3.x*k3.x + m3.y*k3.y + m3.z*k3.z + m3.w*k3.w;
            float msq = m0.x*m0.x + m0.y*m0.y + m0.z*m0.z + m0.w*m0.w
                      + m1.x*m1.x + m1.y*m1.y + m1.z*m1.z + m1.w*m1.w
                      + m2.x*m2.x + m2.y*m2.y + m2.z*m2.z + m2.w*m2.w
                      + m3.x*m3.x + m3.y*m3.y + m3.z*m3.z + m3.w*m3.w;
            dot += __shfl_xor(dot, 1);  msq += __shfl_xor(msq, 1);
            dot += __shfl_xor(dot, 2);  msq += __shfl_xor(msq, 2);
            if (p == 0) {
                float z = bk * dot / sqrtf(msq);
                zbuf1[n] = z;
                lmax1 = fmaxf(lmax1, z);
            }
        }
    }
    #pragma unroll
    for (int o = 1; o < 64; o <<= 1) lmax1 = fmaxf(lmax1, __shfl_xor(lmax1, o));
    if (lane == 0) redA[wv] = lmax1;
    #pragma unroll
    for (int o = 16; o < 64; o <<= 1) {
        acc0.x += __shfl_xor(acc0.x, o);
        acc0.y += __shfl_xor(acc0.y, o);
        acc0.z += __shfl_xor(acc0.z, o);
        acc0.w += __shfl_xor(acc0.w, o);
    }
    if (lane < 16) {
        rred[wv][lane * 4 + 0] = acc0.x;
        rred[wv][lane * 4 + 1] = acc0.y;
        rred[wv][lane * 4 + 2] = acc0.z;
        rred[wv][lane * 4 + 3] = acc0.w;
    }
    __syncthreads();                                   // zbuf1 + redA + rred
    if (t < Dd) {
        float r = 0.f;
        #pragma unroll
        for (int w = 0; w < NW; ++w) r += rred[w][t];
        out_r[(size_t)r0 * Dd + t] = r;
    }
    float zmax1 = redA[0];
    #pragma unroll
    for (int w = 1; w < NW; ++w) zmax1 = fmaxf(zmax1, redA[w]);

    // ---------- mid(r1) ----------
    {
        float e0 = __expf(zbuf1[t] - zmax1);
        float e1 = __expf(zbuf1[t + 1024] - zmax1);
        float ls = e0 + e1;
        zbuf1[t] = e0; zbuf1[t + 1024] = e1;
        #pragma unroll
        for (int o = 1; o < 64; o <<= 1) ls += __shfl_xor(ls, o);
        if (lane == 0) redB[wv] = ls;
    }
    __syncthreads();
    {
        float Zs = 0.f;
        #pragma unroll
        for (int w = 0; w < NW; ++w) Zs += redB[w];
        const float g  = fc1[65];
        const float A  = g / Zs, Cg = 1.f - g;
        const float s0 = fc1[66], s1 = fc1[67], s2 = fc1[68], gamma = fc1[69];
        float wr0, wr1;
        {
            const int n = t, np = (n + 1) & (Nn - 1), nm = (n - 1) & (Nn - 1);
            wr0 = __powf(A * (s0 * zbuf1[np] + s1 * zbuf1[n] + s2 * zbuf1[nm])
                       + Cg * (s0 * wp1[np] + s1 * wp1[n] + s2 * wp1[nm]), gamma);
        }
        {
            const int n = t + 1024, np = (n + 1) & (Nn - 1), nm = (n - 1) & (Nn - 1);
            wr1 = __powf(A * (s0 * zbuf1[np] + s1 * zbuf1[n] + s2 * zbuf1[nm])
                       + Cg * (s0 * wp1[np] + s1 * wp1[n] + s2 * wp1[nm]), gamma);
        }
        float lsum = wr0 + wr1;
        #pragma unroll
        for (int o = 1; o < 64; o <<= 1) lsum += __shfl_xor(lsum, o);
        if (lane == 0) redA[wv] = lsum;
        __syncthreads();
        float Ws = 0.f;
        #pragma unroll
        for (int w = 0; w < NW; ++w) Ws += redA[w];
        const float inv = 1.f / Ws;
        float* ow = out_w + (size_t)r1 * Nn;
        wt1[t] = wr0 * inv;        ow[t] = wr0 * inv;
        wt1[t + 1024] = wr1 * inv; ow[t + 1024] = wr1 * inv;
    }
    __syncthreads();                                   // wt1 final, rred free

    // ---------- pass2(r1): descending n (freshest L3/L2 lines first) ------
    {
        float4 acc = make_float4(0.f, 0.f, 0.f, 0.f);
        #pragma unroll 4
        for (int i = 0; i < Nn / 64; ++i) {
            const int n = (Nn - 64) - i * 64 + grp;
            const float w = wt1[n];
            const float4 m = *(const float4*)&M[mb1 + (size_t)n * Dd + dk * 4];
            acc.x += w * m.x; acc.y += w * m.y;
            acc.z += w * m.z; acc.w += w * m.w;
        }
        #pragma unroll
        for (int o = 16; o < 64; o <<= 1) {
            acc.x += __shfl_xor(acc.x, o);
            acc.y += __shfl_xor(acc.y, o);
            acc.z += __shfl_xor(acc.z, o);
            acc.w += __shfl_xor(acc.w, o);
        }
        if (lane < 16) {
            rred[wv][lane * 4 + 0] = acc.x;
            rred[wv][lane * 4 + 1] = acc.y;
            rred[wv][lane * 4 + 2] = acc.z;
            rred[wv][lane * 4 + 3] = acc.w;
        }
    }
    __syncthreads();
    if (t < Dd) {
        float r = 0.f;
        #pragma unroll
        for (int w = 0; w < NW; ++w) r += rred[w][t];
        out_r[(size_t)r1 * Dd + t] = r;
    }
}

extern "C" void kernel_launch(void* const* d_in, const int* in_sizes, int n_in,
                              void* d_out, int out_size, void* d_ws, size_t ws_size,
                              hipStream_t stream) {
    const float* co    = (const float*)d_in[0];   // (B, C)
    const float* wprev = (const float*)d_in[1];   // (B, N)
    const float* M     = (const float*)d_in[2];   // (B, N, D)
    const float* W     = (const float*)d_in[3];   // (C, 70)
    const float* bias  = (const float*)d_in[4];   // (70,)
    float* out   = (float*)d_out;                 // r_t (B*D) then w_t (B*N)
    float* out_r = out;
    float* out_w = out + (size_t)Bb * Dd;

    ntm_read_head_kernel<<<GRID, BLOCK, 0, stream>>>(co, wprev, M, W, bias, out_r, out_w);
}

// Round 9
// 100.526 us; speedup vs baseline: 1.3269x; 1.3116x over previous
//
#include <hip/hip_runtime.h>
#include <math.h>

// Problem constants (from reference): B,C,N,D,S = 512,256,2048,64,3
constexpr int Bb = 512;
constexpr int Cc = 256;
constexpr int Nn = 2048;
constexpr int Dd = 64;
constexpr int EMIT = Dd + 1 + 1 + 3 + 1;  // 70
constexpr int BLOCK = 1024;
constexpr int NW = BLOCK / 64;            // 16 waves

// ---------------- Kernel A: everything except the final weighted read -----
// fc -> scalars -> pass1 (beta*cos, fused max) -> softmax -> gate+conv+pow
// -> normalize -> out_w.  w_t never touches a scratch buffer.
__global__ __launch_bounds__(BLOCK, 8)
void kA_weights(const float* __restrict__ co,
                const float* __restrict__ wprev,
                const float* __restrict__ M,
                const float* __restrict__ W,
                const float* __restrict__ bias,
                float* __restrict__ out_w)
{
    const int b    = blockIdx.x;
    const int t    = threadIdx.x;
    const int lane = t & 63;
    const int wv   = t >> 6;

    __shared__ __align__(16) float fc[72];     // k[64] + beta,g,s0,s1,s2,gamma,kinv
    __shared__ __align__(16) float zbuf[Nn];   // fc partials -> z -> e
    __shared__ float wpbuf[Nn];
    __shared__ float redA[NW], redB[NW];

    // preload w_prev (hidden under fc)
    {
        const float* wpv = wprev + (size_t)b * Nn;
        wpbuf[t]        = wpv[t];
        wpbuf[t + 1024] = wpv[t + 1024];
    }

    // fc = tanh(co@W + bias), 980-thread partial scheme (scratch = zbuf)
    const float* corow = co + (size_t)b * Cc;
    {
        if (t < 980) {
            const int j = t % EMIT, part = t / EMIT;   // part 0..13
            const int c0 = part * 19;
            const int c1 = (c0 + 19 < Cc) ? c0 + 19 : Cc;
            float s = 0.f;
            for (int c = c0; c < c1; ++c)
                s = fmaf(corow[c], W[(size_t)c * EMIT + j], s);
            zbuf[part * EMIT + j] = s;
        }
        __syncthreads();
        if (t < EMIT) {
            float s = bias[t];
            #pragma unroll
            for (int w = 0; w < 14; ++w) s += zbuf[w * EMIT + t];
            fc[t] = tanhf(s);
        }
    }
    __syncthreads();

    // head scalars (wave 0)
    if (t < 64) {
        float kk  = fc[t];
        float ksq = kk * kk;
        #pragma unroll
        for (int o = 1; o < 64; o <<= 1) ksq += __shfl_xor(ksq, o);
        if (t == 0) {
            float kinv  = 1.f / sqrtf(ksq);
            float beta  = log1pf(expf(fc[Dd]));
            float g     = 1.f / (1.f + expf(-fc[Dd + 1]));
            float f0 = fc[Dd + 2], f1 = fc[Dd + 3], f2 = fc[Dd + 4];
            float mx = fmaxf(f0, fmaxf(f1, f2));
            float e0 = expf(f0 - mx), e1 = expf(f1 - mx), e2 = expf(f2 - mx);
            float ei = 1.f / (e0 + e1 + e2);
            float gamma = 1.f + log1pf(expf(fc[Dd + 5]));
            fc[64] = beta; fc[65] = g;
            fc[66] = e0 * ei; fc[67] = e1 * ei; fc[68] = e2 * ei;
            fc[69] = gamma; fc[70] = kinv;
        }
    }
    __syncthreads();

    // pass1: z[n] = beta*cos(k, M[b,n,:]), fused running max
    const size_t mbase = (size_t)b * Nn * Dd;
    float lmax = -3.4e38f;
    {
        const int rg = t >> 2, p = t & 3;
        const float bk = fc[64] * fc[70];          // beta / |k|
        const float4 k0 = *(const float4*)&fc[p * 16 + 0];
        const float4 k1 = *(const float4*)&fc[p * 16 + 4];
        const float4 k2 = *(const float4*)&fc[p * 16 + 8];
        const float4 k3 = *(const float4*)&fc[p * 16 + 12];
        #pragma unroll 2
        for (int n0 = 0; n0 < Nn; n0 += 256) {
            const int n = n0 + rg;
            const float4* mr = (const float4*)&M[mbase + (size_t)n * Dd + p * 16];
            const float4 m0 = mr[0], m1 = mr[1], m2 = mr[2], m3 = mr[3];
            float dot = m0.x*k0.x + m0.y*k0.y + m0.z*k0.z + m0.w*k0.w
                      + m1.x*k1.x + m1.y*k1.y + m1.z*k1.z + m1.w*k1.w
                      + m2.x*k2.x + m2.y*k2.y + m2.z*k2.z + m2.w*k2.w
                      + m3.x*k3.x + m3.y*k3.y + m3.z*k3.z + m3.w*k3.w;
            float msq = m0.x*m0.x + m0.y*m0.y + m0.z*m0.z + m0.w*m0.w
                      + m1.x*m1.x + m1.y*m1.y + m1.z*m1.z + m1.w*m1.w
                      + m2.x*m2.x + m2.y*m2.y + m2.z*m2.z + m2.w*m2.w
                      + m3.x*m3.x + m3.y*m3.y + m3.z*m3.z + m3.w*m3.w;
            dot += __shfl_xor(dot, 1);  msq += __shfl_xor(msq, 1);
            dot += __shfl_xor(dot, 2);  msq += __shfl_xor(msq, 2);
            if (p == 0) {
                float z = bk * dot / sqrtf(msq);
                zbuf[n] = z;
                lmax = fmaxf(lmax, z);
            }
        }
    }
    #pragma unroll
    for (int o = 1; o < 64; o <<= 1) lmax = fmaxf(lmax, __shfl_xor(lmax, o));
    if (lane == 0) redA[wv] = lmax;
    __syncthreads();                               // zbuf + redA ready
    float zmax = redA[0];
    #pragma unroll
    for (int w = 1; w < NW; ++w) zmax = fmaxf(zmax, redA[w]);

    // exp + sum
    float ls;
    {
        float e0 = __expf(zbuf[t] - zmax);
        float e1 = __expf(zbuf[t + 1024] - zmax);
        ls = e0 + e1;
        zbuf[t] = e0; zbuf[t + 1024] = e1;
    }
    #pragma unroll
    for (int o = 1; o < 64; o <<= 1) ls += __shfl_xor(ls, o);
    if (lane == 0) redB[wv] = ls;
    __syncthreads();                               // e in zbuf + redB ready
    float Zs = 0.f;
    #pragma unroll
    for (int w = 0; w < NW; ++w) Zs += redB[w];

    // conv + pow + sum (gate folded), then normalize straight to out_w
    const float g  = fc[65];
    const float A  = g / Zs, Cg = 1.f - g;
    const float s0 = fc[66], s1 = fc[67], s2 = fc[68], gamma = fc[69];
    float wr0, wr1;
    {
        const int n = t, np = (n + 1) & (Nn - 1), nm = (n - 1) & (Nn - 1);
        wr0 = __powf(A * (s0 * zbuf[np] + s1 * zbuf[n] + s2 * zbuf[nm])
                   + Cg * (s0 * wpbuf[np] + s1 * wpbuf[n] + s2 * wpbuf[nm]), gamma);
    }
    {
        const int n = t + 1024, np = (n + 1) & (Nn - 1), nm = (n - 1) & (Nn - 1);
        wr1 = __powf(A * (s0 * zbuf[np] + s1 * zbuf[n] + s2 * zbuf[nm])
                   + Cg * (s0 * wpbuf[np] + s1 * wpbuf[n] + s2 * wpbuf[nm]), gamma);
    }
    float lsum = wr0 + wr1;
    #pragma unroll
    for (int o = 1; o < 64; o <<= 1) lsum += __shfl_xor(lsum, o);
    if (lane == 0) redA[wv] = lsum;
    __syncthreads();
    float Ws = 0.f;
    #pragma unroll
    for (int w = 0; w < NW; ++w) Ws += redA[w];

    const float inv = 1.f / Ws;
    float* ow = out_w + (size_t)b * Nn;
    ow[t]        = wr0 * inv;
    ow[t + 1024] = wr1 * inv;
}

// ---------------- Kernel B: r_t[d] = sum_n w_t[n] * M[b,n,d] --------------
__global__ __launch_bounds__(BLOCK, 8)
void kB_read(const float* __restrict__ M, const float* __restrict__ out_w,
             float* __restrict__ out_r)
{
    const int b = blockIdx.x, t = threadIdx.x;
    const int lane = t & 63, wv = t >> 6;
    __shared__ float wtbuf[Nn];
    __shared__ float rred[NW][Dd];

    const float* wrow = out_w + (size_t)b * Nn;
    wtbuf[t]        = wrow[t];
    wtbuf[t + 1024] = wrow[t + 1024];
    __syncthreads();

    const size_t mbase = (size_t)b * Nn * Dd;
    const int grp = t >> 4;          // 64 rows per iteration
    const int dk  = t & 15;
    float4 acc = make_float4(0.f, 0.f, 0.f, 0.f);
    #pragma unroll 4
    for (int i = 0; i < Nn / 64; ++i) {
        const int n = (Nn - 64) - i * 64 + grp;   // descending: freshest lines first
        const float w = wtbuf[n];
        const float4 m = *(const float4*)&M[mbase + (size_t)n * Dd + dk * 4];
        acc.x += w * m.x; acc.y += w * m.y;
        acc.z += w * m.z; acc.w += w * m.w;
    }
    #pragma unroll
    for (int o = 16; o < 64; o <<= 1) {
        acc.x += __shfl_xor(acc.x, o);
        acc.y += __shfl_xor(acc.y, o);
        acc.z += __shfl_xor(acc.z, o);
        acc.w += __shfl_xor(acc.w, o);
    }
    if (lane < 16) {
        rred[wv][lane * 4 + 0] = acc.x;
        rred[wv][lane * 4 + 1] = acc.y;
        rred[wv][lane * 4 + 2] = acc.z;
        rred[wv][lane * 4 + 3] = acc.w;
    }
    __syncthreads();
    if (t < Dd) {
        float r = 0.f;
        #pragma unroll
        for (int w = 0; w < NW; ++w) r += rred[w][t];
        out_r[(size_t)b * Dd + t] = r;
    }
}

extern "C" void kernel_launch(void* const* d_in, const int* in_sizes, int n_in,
                              void* d_out, int out_size, void* d_ws, size_t ws_size,
                              hipStream_t stream) {
    const float* co    = (const float*)d_in[0];   // (B, C)
    const float* wprev = (const float*)d_in[1];   // (B, N)
    const float* M     = (const float*)d_in[2];   // (B, N, D)
    const float* W     = (const float*)d_in[3];   // (C, 70)
    const float* bias  = (const float*)d_in[4];   // (70,)
    float* out   = (float*)d_out;                 // r_t (B*D) then w_t (B*N)
    float* out_r = out;
    float* out_w = out + (size_t)Bb * Dd;

    kA_weights<<<Bb, BLOCK, 0, stream>>>(co, wprev, M, W, bias, out_w);
    kB_read   <<<Bb, BLOCK, 0, stream>>>(M, out_w, out_r);
}

// Round 11
// 93.170 us; speedup vs baseline: 1.4316x; 1.0790x over previous
//
#include <hip/hip_runtime.h>
#include <math.h>

// Problem constants (from reference): B,C,N,D,S = 512,256,2048,64,3
constexpr int Bb = 512;
constexpr int Cc = 256;
constexpr int Nn = 2048;
constexpr int Dd = 64;
constexpr int EMIT = Dd + 1 + 1 + 3 + 1;  // 70
constexpr int BLOCK = 1024;
constexpr int NW = BLOCK / 64;            // waves per block = 16

__global__ __launch_bounds__(BLOCK, 8)
void ntm_read_head_kernel(const float* __restrict__ co,
                          const float* __restrict__ wprev,
                          const float* __restrict__ M,
                          const float* __restrict__ W,
                          const float* __restrict__ bias,
                          float* __restrict__ out_r,
                          float* __restrict__ out_w)
{
    const int b    = blockIdx.x;
    const int t    = threadIdx.x;
    const int lane = t & 63;
    const int wv   = t >> 6;

    __shared__ __align__(16) float fc[72];     // k[64] + beta,g,s0,s1,s2,gamma,kinv
    __shared__ __align__(16) float zbuf[Nn];   // fc partials -> z -> e -> w_t
    __shared__ float wpbuf[Nn];                // preloaded w_prev row
    __shared__ float redA[NW], redB[NW];
    __shared__ float rred[NW][Dd];

    // ---------- preload w_prev row (overlaps fc) ----------
    {
        const float* wpv = wprev + (size_t)b * Nn;
        wpbuf[t]        = wpv[t];
        wpbuf[t + 1024] = wpv[t + 1024];
    }

    // ---------- fc = tanh(co[b] @ W + bias), scratch in zbuf ----------
    const float* corow = co + (size_t)b * Cc;
    {
        if (t < 980) {
            const int j = t % EMIT, part = t / EMIT;   // part 0..13
            const int c0 = part * 19;
            const int c1 = (c0 + 19 < Cc) ? c0 + 19 : Cc;
            float s = 0.f;
            for (int c = c0; c < c1; ++c)
                s = fmaf(corow[c], W[(size_t)c * EMIT + j], s);
            zbuf[part * EMIT + j] = s;
        }
        __syncthreads();
        if (t < EMIT) {
            float s = bias[t];
            #pragma unroll
            for (int w = 0; w < 14; ++w) s += zbuf[w * EMIT + t];
            fc[t] = tanhf(s);
        }
    }
    __syncthreads();

    // ---------- head scalars (wave 0) ----------
    if (t < 64) {
        float kk  = fc[t];
        float ksq = kk * kk;
        #pragma unroll
        for (int o = 1; o < 64; o <<= 1) ksq += __shfl_xor(ksq, o);
        if (t == 0) {
            float kinv  = 1.f / sqrtf(ksq);
            float beta  = log1pf(expf(fc[Dd]));
            float g     = 1.f / (1.f + expf(-fc[Dd + 1]));
            float f0 = fc[Dd + 2], f1 = fc[Dd + 3], f2 = fc[Dd + 4];
            float mx = fmaxf(f0, fmaxf(f1, f2));
            float e0 = expf(f0 - mx), e1 = expf(f1 - mx), e2 = expf(f2 - mx);
            float ei = 1.f / (e0 + e1 + e2);
            float gamma = 1.f + log1pf(expf(fc[Dd + 5]));
            fc[64] = beta; fc[65] = g;
            fc[66] = e0 * ei; fc[67] = e1 * ei; fc[68] = e2 * ei;
            fc[69] = gamma; fc[70] = kinv;
        }
    }
    __syncthreads();

    // ---------- pass 1: z[n] = beta*cos(k, M[b,n,:]), fused running max ----
    const size_t mbase = (size_t)b * Nn * Dd;
    float lmax = -3.4e38f;
    {
        const int rg = t >> 2, p = t & 3;
        const float bk = fc[64] * fc[70];          // beta / |k|
        const float4 k0 = *(const float4*)&fc[p * 16 + 0];
        const float4 k1 = *(const float4*)&fc[p * 16 + 4];
        const float4 k2 = *(const float4*)&fc[p * 16 + 8];
        const float4 k3 = *(const float4*)&fc[p * 16 + 12];
        #pragma unroll 2
        for (int n0 = 0; n0 < Nn; n0 += 256) {
            const int n = n0 + rg;
            const float4* mr = (const float4*)&M[mbase + (size_t)n * Dd + p * 16];
            const float4 m0 = mr[0], m1 = mr[1], m2 = mr[2], m3 = mr[3];
            float dot = m0.x*k0.x + m0.y*k0.y + m0.z*k0.z + m0.w*k0.w
                      + m1.x*k1.x + m1.y*k1.y + m1.z*k1.z + m1.w*k1.w
                      + m2.x*k2.x + m2.y*k2.y + m2.z*k2.z + m2.w*k2.w
                      + m3.x*k3.x + m3.y*k3.y + m3.z*k3.z + m3.w*k3.w;
            float msq = m0.x*m0.x + m0.y*m0.y + m0.z*m0.z + m0.w*m0.w
                      + m1.x*m1.x + m1.y*m1.y + m1.z*m1.z + m1.w*m1.w
                      + m2.x*m2.x + m2.y*m2.y + m2.z*m2.z + m2.w*m2.w
                      + m3.x*m3.x + m3.y*m3.y + m3.z*m3.z + m3.w*m3.w;
            dot += __shfl_xor(dot, 1);  msq += __shfl_xor(msq, 1);
            dot += __shfl_xor(dot, 2);  msq += __shfl_xor(msq, 2);
            if (p == 0) {
                float z = bk * dot / sqrtf(msq);
                zbuf[n] = z;
                lmax = fmaxf(lmax, z);
            }
        }
    }
    #pragma unroll
    for (int o = 1; o < 64; o <<= 1) lmax = fmaxf(lmax, __shfl_xor(lmax, o));
    if (lane == 0) redA[wv] = lmax;
    __syncthreads();                               // zbuf + redA ready
    float zmax = redA[0];
    #pragma unroll
    for (int w = 1; w < NW; ++w) zmax = fmaxf(zmax, redA[w]);

    // ---------- exp + sum ----------
    float ls;
    {
        float e0 = __expf(zbuf[t] - zmax);
        float e1 = __expf(zbuf[t + 1024] - zmax);
        ls = e0 + e1;
        zbuf[t] = e0; zbuf[t + 1024] = e1;
    }
    #pragma unroll
    for (int o = 1; o < 64; o <<= 1) ls += __shfl_xor(ls, o);
    if (lane == 0) redB[wv] = ls;
    __syncthreads();                               // e in zbuf + redB ready
    float Zs = 0.f;
    #pragma unroll
    for (int w = 0; w < NW; ++w) Zs += redB[w];

    // ---------- conv + pow + sum (gate folded algebraically) ----------
    const float g  = fc[65];
    const float A  = g / Zs, Cg = 1.f - g;
    const float s0 = fc[66], s1 = fc[67], s2 = fc[68], gamma = fc[69];
    float wr0, wr1;
    {
        const int n = t, np = (n + 1) & (Nn - 1), nm = (n - 1) & (Nn - 1);
        wr0 = __powf(A * (s0 * zbuf[np] + s1 * zbuf[n] + s2 * zbuf[nm])
                   + Cg * (s0 * wpbuf[np] + s1 * wpbuf[n] + s2 * wpbuf[nm]), gamma);
    }
    {
        const int n = t + 1024, np = (n + 1) & (Nn - 1), nm = (n - 1) & (Nn - 1);
        wr1 = __powf(A * (s0 * zbuf[np] + s1 * zbuf[n] + s2 * zbuf[nm])
                   + Cg * (s0 * wpbuf[np] + s1 * wpbuf[n] + s2 * wpbuf[nm]), gamma);
    }
    float lsum = wr0 + wr1;
    #pragma unroll
    for (int o = 1; o < 64; o <<= 1) lsum += __shfl_xor(lsum, o);
    if (lane == 0) redA[wv] = lsum;
    __syncthreads();                               // all conv reads of zbuf done
    float Ws = 0.f;
    #pragma unroll
    for (int w = 0; w < NW; ++w) Ws += redA[w];

    // ---------- normalize: store w_t into zbuf (reuse) + out_w ----------
    {
        const float inv = 1.f / Ws;
        float* ow = out_w + (size_t)b * Nn;
        float v0 = wr0 * inv, v1 = wr1 * inv;
        zbuf[t] = v0;        ow[t] = v0;
        zbuf[t + 1024] = v1; ow[t + 1024] = v1;
    }
    __syncthreads();                               // w_t final in zbuf

    // ---------- pass 2: r_t[d] = sum_n w_t[n]*M[b,n,d], descending n ------
    {
        const int grp = t >> 4;      // 64 rows per iteration
        const int dk  = t & 15;
        float4 acc = make_float4(0.f, 0.f, 0.f, 0.f);
        #pragma unroll 8
        for (int i = 0; i < Nn / 64; ++i) {
            const int n = (Nn - 64) - i * 64 + grp;   // freshest L3 lines first
            const float w = zbuf[n];
            const float4 m = *(const float4*)&M[mbase + (size_t)n * Dd + dk * 4];
            acc.x += w * m.x; acc.y += w * m.y;
            acc.z += w * m.z; acc.w += w * m.w;
        }
        #pragma unroll
        for (int o = 16; o < 64; o <<= 1) {
            acc.x += __shfl_xor(acc.x, o);
            acc.y += __shfl_xor(acc.y, o);
            acc.z += __shfl_xor(acc.z, o);
            acc.w += __shfl_xor(acc.w, o);
        }
        if (lane < 16) {
            rred[wv][lane * 4 + 0] = acc.x;
            rred[wv][lane * 4 + 1] = acc.y;
            rred[wv][lane * 4 + 2] = acc.z;
            rred[wv][lane * 4 + 3] = acc.w;
        }
    }
    __syncthreads();
    if (t < Dd) {
        float r = 0.f;
        #pragma unroll
        for (int w = 0; w < NW; ++w) r += rred[w][t];
        out_r[(size_t)b * Dd + t] = r;
    }
}

extern "C" void kernel_launch(void* const* d_in, const int* in_sizes, int n_in,
                              void* d_out, int out_size, void* d_ws, size_t ws_size,
                              hipStream_t stream) {
    const float* co    = (const float*)d_in[0];   // (B, C)
    const float* wprev = (const float*)d_in[1];   // (B, N)
    const float* M     = (const float*)d_in[2];   // (B, N, D)
    const float* W     = (const float*)d_in[3];   // (C, 70)
    const float* bias  = (const float*)d_in[4];   // (70,)
    float* out   = (float*)d_out;                 // r_t (B*D) then w_t (B*N)
    float* out_r = out;
    float* out_w = out + (size_t)Bb * Dd;

    ntm_read_head_kernel<<<Bb, BLOCK, 0, stream>>>(co, wprev, M, W, bias, out_r, out_w);
}

// Round 12
// 88.290 us; speedup vs baseline: 1.5108x; 1.0553x over previous
//
#include <hip/hip_runtime.h>
#include <math.h>

// Problem constants (from reference): B,C,N,D,S = 512,256,2048,64,3
constexpr int Bb = 512;
constexpr int Cc = 256;
constexpr int Nn = 2048;
constexpr int Dd = 64;
constexpr int EMIT = Dd + 1 + 1 + 3 + 1;  // 70
constexpr int BLOCK = 1024;
constexpr int NW = BLOCK / 64;            // waves per block = 16

__global__ __launch_bounds__(BLOCK, 8)
void ntm_read_head_kernel(const float* __restrict__ co,
                          const float* __restrict__ wprev,
                          const float* __restrict__ M,
                          const float* __restrict__ W,
                          const float* __restrict__ bias,
                          float* __restrict__ out_r,
                          float* __restrict__ out_w)
{
    const int b    = blockIdx.x;
    const int t    = threadIdx.x;
    const int lane = t & 63;
    const int wv   = t >> 6;

    __shared__ __align__(16) float fc[EMIT + 2];   // tanh(co@W+b)
    __shared__ float sc[8];                        // beta,g,s0,s1,s2,gamma,1/kmag
    __shared__ __align__(16) float zbuf[Nn];       // fc partials -> z -> e
    __shared__ float wgbuf[Nn];                    // gated weights
    __shared__ float wtbuf[Nn];                    // raised/normalized weights
    __shared__ float red[NW];                      // block-reduce scratch
    __shared__ float rred[NW][Dd];                 // r_t partial per wave

    // ---------- fc = tanh(co[b] @ W + bias) ----------
    // 980 threads: j = t%70 (output), part = t/70 (c-slice of 19).
    // W reads are coalesced along j (70 consecutive floats per c).
    const float* corow = co + (size_t)b * Cc;
    {
        float* fcp = zbuf;                 // reuse zbuf as 14x70 partial buffer
        if (t < 980) {
            const int j    = t % EMIT;
            const int part = t / EMIT;     // 0..13
            const int c0 = part * 19;
            const int c1 = (c0 + 19 < Cc) ? c0 + 19 : Cc;
            float s = 0.f;
            for (int c = c0; c < c1; ++c)
                s = fmaf(corow[c], W[(size_t)c * EMIT + j], s);
            fcp[part * EMIT + j] = s;
        }
        __syncthreads();
        if (t < EMIT) {
            float s = bias[t];
            #pragma unroll
            for (int w = 0; w < 14; ++w) s += fcp[w * EMIT + t];
            fc[t] = tanhf(s);
        }
    }
    __syncthreads();

    // ---------- head scalars (wave 0) ----------
    if (t < 64) {
        float kk  = fc[t];
        float ksq = kk * kk;
        #pragma unroll
        for (int o = 1; o < 64; o <<= 1) ksq += __shfl_xor(ksq, o);
        if (t == 0) {
            float kmag  = sqrtf(ksq);
            float beta  = log1pf(expf(fc[Dd]));          // softplus
            float g     = 1.f / (1.f + expf(-fc[Dd + 1]));
            float f0 = fc[Dd + 2], f1 = fc[Dd + 3], f2 = fc[Dd + 4];
            float mx = fmaxf(f0, fmaxf(f1, f2));
            float e0 = expf(f0 - mx), e1 = expf(f1 - mx), e2 = expf(f2 - mx);
            float ei = 1.f / (e0 + e1 + e2);
            float gamma = 1.f + log1pf(expf(fc[Dd + 5]));
            sc[0] = beta; sc[1] = g;
            sc[2] = e0 * ei; sc[3] = e1 * ei; sc[4] = e2 * ei;
            sc[5] = gamma; sc[6] = 1.f / kmag;
        }
    }
    __syncthreads();

    // ---------- pass 1: z[n] = beta * cos(k, M[b,n,:]) ----------
    // 4 lanes per row, 4 independent float4 loads per lane (16 d each),
    // then only 2 shfl stages x 2 values.
    const size_t mbase = (size_t)b * Nn * Dd;
    {
        const int rg = t >> 2;           // 0..255 row within slab
        const int p  = t & 3;            // lane within row
        const float beta = sc[0];
        const float kinv = sc[6];
        const float4 k0 = *(const float4*)&fc[p * 16 + 0];
        const float4 k1 = *(const float4*)&fc[p * 16 + 4];
        const float4 k2 = *(const float4*)&fc[p * 16 + 8];
        const float4 k3 = *(const float4*)&fc[p * 16 + 12];
        for (int n0 = 0; n0 < Nn; n0 += BLOCK / 4) {
            const int n = n0 + rg;
            const float4* mr = (const float4*)&M[mbase + (size_t)n * Dd + p * 16];
            const float4 m0 = mr[0];
            const float4 m1 = mr[1];
            const float4 m2 = mr[2];
            const float4 m3 = mr[3];
            float dot = m0.x*k0.x + m0.y*k0.y + m0.z*k0.z + m0.w*k0.w
                      + m1.x*k1.x + m1.y*k1.y + m1.z*k1.z + m1.w*k1.w
                      + m2.x*k2.x + m2.y*k2.y + m2.z*k2.z + m2.w*k2.w
                      + m3.x*k3.x + m3.y*k3.y + m3.z*k3.z + m3.w*k3.w;
            float msq = m0.x*m0.x + m0.y*m0.y + m0.z*m0.z + m0.w*m0.w
                      + m1.x*m1.x + m1.y*m1.y + m1.z*m1.z + m1.w*m1.w
                      + m2.x*m2.x + m2.y*m2.y + m2.z*m2.z + m2.w*m2.w
                      + m3.x*m3.x + m3.y*m3.y + m3.z*m3.z + m3.w*m3.w;
            dot += __shfl_xor(dot, 1);
            msq += __shfl_xor(msq, 1);
            dot += __shfl_xor(dot, 2);
            msq += __shfl_xor(msq, 2);
            if (p == 0) zbuf[n] = beta * dot * kinv / sqrtf(msq);
        }
    }
    __syncthreads();

    // ---------- softmax over n (block-wide) ----------
    float lm = -3.4e38f;
    for (int n = t; n < Nn; n += BLOCK) lm = fmaxf(lm, zbuf[n]);
    #pragma unroll
    for (int o = 1; o < 64; o <<= 1) lm = fmaxf(lm, __shfl_xor(lm, o));
    if (lane == 0) red[wv] = lm;
    __syncthreads();
    float zmax = red[0];
    #pragma unroll
    for (int w = 1; w < NW; ++w) zmax = fmaxf(zmax, red[w]);
    __syncthreads();                                  // protect red before reuse

    float ls = 0.f;
    for (int n = t; n < Nn; n += BLOCK) {
        float e = expf(zbuf[n] - zmax);
        zbuf[n] = e;
        ls += e;
    }
    #pragma unroll
    for (int o = 1; o < 64; o <<= 1) ls += __shfl_xor(ls, o);
    if (lane == 0) red[wv] = ls;
    __syncthreads();
    float Zs = 0.f;
    #pragma unroll
    for (int w = 0; w < NW; ++w) Zs += red[w];

    // ---------- gate with w_prev ----------
    {
        const float g = sc[1];
        const float invZ = 1.f / Zs;
        const float* wpv = wprev + (size_t)b * Nn;
        for (int n = t; n < Nn; n += BLOCK)
            wgbuf[n] = g * zbuf[n] * invZ + (1.f - g) * wpv[n];
    }
    __syncthreads();   // wgbuf ready (also protects red before next write)

    // ---------- circular conv (S=3) + pow + sum ----------
    float lsum = 0.f;
    {
        const float s0 = sc[2], s1 = sc[3], s2 = sc[4], gamma = sc[5];
        for (int n = t; n < Nn; n += BLOCK) {
            float wt_ = s0 * wgbuf[(n + 1) & (Nn - 1)]
                      + s1 * wgbuf[n]
                      + s2 * wgbuf[(n - 1) & (Nn - 1)];
            float wr = powf(wt_, gamma);
            wtbuf[n] = wr;
            lsum += wr;
        }
    }
    #pragma unroll
    for (int o = 1; o < 64; o <<= 1) lsum += __shfl_xor(lsum, o);
    if (lane == 0) red[wv] = lsum;
    __syncthreads();
    float Ws = 0.f;
    #pragma unroll
    for (int w = 0; w < NW; ++w) Ws += red[w];

    // ---------- normalize + store w_t ----------
    {
        const float inv = 1.f / Ws;
        float* ow = out_w + (size_t)b * Nn;
        #pragma unroll
        for (int k = 0; k < 2; ++k) {
            const int n = t + k * 1024;
            float v = wtbuf[n] * inv;
            wtbuf[n] = v;
            ow[n] = v;
        }
    }
    __syncthreads();   // wtbuf final for pass 2

    // ---------- pass 2: r_t[d] = sum_n w_t[n] * M[b,n,d] ----------
    {
        const int grp = t >> 4;      // 64 row-groups
        const int dk  = t & 15;      // 16 lanes per row, float4 each
        float4 acc = make_float4(0.f, 0.f, 0.f, 0.f);
        #pragma unroll 2
        for (int n = grp; n < Nn; n += BLOCK / 16) {
            const float w = wtbuf[n];
            const float4 m = *(const float4*)&M[mbase + (size_t)n * Dd + dk * 4];
            acc.x += w * m.x; acc.y += w * m.y;
            acc.z += w * m.z; acc.w += w * m.w;
        }
        #pragma unroll
        for (int o = 16; o < 64; o <<= 1) {
            acc.x += __shfl_xor(acc.x, o);
            acc.y += __shfl_xor(acc.y, o);
            acc.z += __shfl_xor(acc.z, o);
            acc.w += __shfl_xor(acc.w, o);
        }
        if (lane < 16) {
            rred[wv][lane * 4 + 0] = acc.x;
            rred[wv][lane * 4 + 1] = acc.y;
            rred[wv][lane * 4 + 2] = acc.z;
            rred[wv][lane * 4 + 3] = acc.w;
        }
    }
    __syncthreads();
    if (t < Dd) {
        float r = 0.f;
        #pragma unroll
        for (int w = 0; w < NW; ++w) r += rred[w][t];
        out_r[(size_t)b * Dd + t] = r;
    }
}

extern "C" void kernel_launch(void* const* d_in, const int* in_sizes, int n_in,
                              void* d_out, int out_size, void* d_ws, size_t ws_size,
                              hipStream_t stream) {
    const float* co    = (const float*)d_in[0];   // (B, C)
    const float* wprev = (const float*)d_in[1];   // (B, N)
    const float* M     = (const float*)d_in[2];   // (B, N, D)
    const float* W     = (const float*)d_in[3];   // (C, 70)
    const float* bias  = (const float*)d_in[4];   // (70,)
    float* out = (float*)d_out;                   // r_t (B*D) then w_t (B*N)
    float* out_r = out;
    float* out_w = out + (size_t)Bb * Dd;

    ntm_read_head_kernel<<<Bb, BLOCK, 0, stream>>>(co, wprev, M, W, bias, out_r, out_w);
}